// Round 1
// baseline (508.570 us; speedup 1.0000x reference)
//
#include <hip/hip_runtime.h>
#include <hip/hip_bf16.h>

#define SPIX 1000
#define NCLS 21
#define PP (512*512)          // pixels per image, 2^18
#define NB_IMG 8
#define EPB (NCLS*PP)         // elements per batch in pred

// ws layout (floats)
#define R_OFF   0                      // [8][21][1000]
#define TR_OFF  (NB_IMG*NCLS*SPIX)     // [8]
#define NS_OFF  (TR_OFF + NB_IMG)      // [1] norm^2
#define CNT_OFF (NS_OFF + 1)           // [1] valid count
#define WS_FLOATS (CNT_OFF + 1)

__global__ void normsq_kernel(const float* __restrict__ W, float* __restrict__ out, int n4) {
    const float4* W4 = (const float4*)W;
    float s = 0.f;
    for (int i = blockIdx.x * blockDim.x + threadIdx.x; i < n4; i += gridDim.x * blockDim.x) {
        float4 v = W4[i];
        s += v.x*v.x + v.y*v.y + v.z*v.z + v.w*v.w;
    }
    #pragma unroll
    for (int off = 32; off; off >>= 1) s += __shfl_xor(s, off);
    if ((threadIdx.x & 63) == 0) atomicAdd(out, s);
}

__global__ void count_kernel(const int* __restrict__ seg, float* __restrict__ out, int n4) {
    const int4* s4 = (const int4*)seg;
    int cnt = 0;
    for (int i = blockIdx.x * blockDim.x + threadIdx.x; i < n4; i += gridDim.x * blockDim.x) {
        int4 v = s4[i];
        cnt += ((unsigned)v.x < SPIX) + ((unsigned)v.y < SPIX) + ((unsigned)v.z < SPIX) + ((unsigned)v.w < SPIX);
    }
    float c = (float)cnt;
    #pragma unroll
    for (int off = 32; off; off >>= 1) c += __shfl_xor(c, off);
    if ((threadIdx.x & 63) == 0) atomicAdd(out, c);
}

// R[b,c,s] += pred[b, j] for j = cc*P + spatial; f = spatial*21+cc; c=f>>18; p=f&(P-1); s=seg[b,p]
__global__ __launch_bounds__(1024) void scatter_kernel(const float* __restrict__ pred,
                                                       const int* __restrict__ seg,
                                                       float* __restrict__ Rout, int nb) {
    __shared__ float Rl[NCLS * SPIX];   // 84 KB
    const int b = blockIdx.y;
    for (int idx = threadIdx.x; idx < NCLS * SPIX; idx += 1024) Rl[idx] = 0.f;
    __syncthreads();

    const float4* pred4 = (const float4*)(pred + (size_t)b * EPB);
    const int* segb = seg + (size_t)b * PP;
    const int n4 = EPB / 4;   // 1376256
    for (int q = blockIdx.x * 1024 + threadIdx.x; q < n4; q += nb * 1024) {
        float4 v = pred4[q];
        int j = q * 4;
        #pragma unroll
        for (int k = 0; k < 4; ++k) {
            int jj = j + k;
            int spatial = jj & (PP - 1);
            int cc = jj >> 18;
            int f = spatial * NCLS + cc;
            int c = f >> 18;
            int p = f & (PP - 1);
            int s = segb[p];
            if ((unsigned)s < SPIX) atomicAdd(&Rl[c * SPIX + s], (&v.x)[k]);
        }
    }
    __syncthreads();

    float* Rb = Rout + (size_t)b * NCLS * SPIX;
    for (int idx = threadIdx.x; idx < NCLS * SPIX; idx += 1024) {
        float vv = Rl[idx];
        if (vv != 0.f) atomicAdd(&Rb[idx], vv);
    }
}

// trace[b] = sum_{s,t} L[b,s,t] * sum_c R[b,c,s]*R[b,c,t]
__global__ __launch_bounds__(1024) void trace_kernel(const float* __restrict__ L,
                                                     const float* __restrict__ R,
                                                     float* __restrict__ traces) {
    __shared__ float Rl[NCLS * SPIX];   // 84 KB
    const int b = blockIdx.y;
    const float* Rb = R + (size_t)b * NCLS * SPIX;
    for (int idx = threadIdx.x; idx < NCLS * SPIX; idx += 1024) Rl[idx] = Rb[idx];
    __syncthreads();

    const int wave = threadIdx.x >> 6;
    const int lane = threadIdx.x & 63;
    const float* Lb = L + (size_t)b * SPIX * SPIX;

    int s0 = blockIdx.x * 32 + wave * 2;   // each wave: 2 rows
    int s1 = s0 + 1;
    bool v0 = s0 < SPIX, v1 = s1 < SPIX;

    float acc0[NCLS], acc1[NCLS];
    #pragma unroll
    for (int c = 0; c < NCLS; ++c) { acc0[c] = 0.f; acc1[c] = 0.f; }

    const float4* L40 = (const float4*)(Lb + (size_t)(v0 ? s0 : 0) * SPIX);
    const float4* L41 = (const float4*)(Lb + (size_t)(v1 ? s1 : 0) * SPIX);

    #pragma unroll
    for (int it = 0; it < 4; ++it) {
        int idx = it * 64 + lane;          // float4 index within row, 0..249
        if (idx < SPIX / 4) {
            float4 l0 = v0 ? L40[idx] : make_float4(0.f, 0.f, 0.f, 0.f);
            float4 l1 = v1 ? L41[idx] : make_float4(0.f, 0.f, 0.f, 0.f);
            #pragma unroll
            for (int c = 0; c < NCLS; ++c) {
                float4 r = *(const float4*)&Rl[c * SPIX + idx * 4];
                acc0[c] += l0.x * r.x + l0.y * r.y + l0.z * r.z + l0.w * r.w;
                acc1[c] += l1.x * r.x + l1.y * r.y + l1.z * r.z + l1.w * r.w;
            }
        }
    }

    float partial = 0.f;
    #pragma unroll
    for (int c = 0; c < NCLS; ++c) {
        if (v0) partial += Rl[c * SPIX + s0] * acc0[c];
        if (v1) partial += Rl[c * SPIX + s1] * acc1[c];
    }
    #pragma unroll
    for (int off = 32; off; off >>= 1) partial += __shfl_xor(partial, off);
    if (lane == 0) atomicAdd(&traces[b], partial);
}

__global__ void finalize_kernel(const float* __restrict__ ws, float* __restrict__ out) {
    if (threadIdx.x == 0) {
        float denom = ws[CNT_OFF] + 1e-16f;
        float inv2 = 1.f / (denom * denom);
        float t = 0.f;
        for (int b = 0; b < NB_IMG; ++b) t += ws[TR_OFF + b];
        out[0] = (2.f / sqrtf(ws[NS_OFF])) * t * inv2 / (float)NB_IMG;
    }
}

extern "C" void kernel_launch(void* const* d_in, const int* in_sizes, int n_in,
                              void* d_out, int out_size, void* d_ws, size_t ws_size,
                              hipStream_t stream) {
    const float* pred = (const float*)d_in[0];
    const float* Wc   = (const float*)d_in[1];
    const float* Lc   = (const float*)d_in[2];
    const int*   seg  = (const int*)d_in[3];
    float* ws = (float*)d_ws;
    float* out = (float*)d_out;

    hipMemsetAsync(d_ws, 0, WS_FLOATS * sizeof(float), stream);

    normsq_kernel<<<1024, 256, 0, stream>>>(Wc, ws + NS_OFF, (NB_IMG * SPIX * SPIX) / 4);
    count_kernel<<<512, 256, 0, stream>>>(seg, ws + CNT_OFF, (NB_IMG * PP) / 4);

    const int nb = 32;
    scatter_kernel<<<dim3(nb, NB_IMG), 1024, 0, stream>>>(pred, seg, ws + R_OFF, nb);

    trace_kernel<<<dim3(32, NB_IMG), 1024, 0, stream>>>(Lc, ws + R_OFF, ws + TR_OFF);

    finalize_kernel<<<1, 64, 0, stream>>>(ws, out);
}

// Round 2
// 399.918 us; speedup vs baseline: 1.2717x; 1.2717x over previous
//
#include <hip/hip_runtime.h>
#include <hip/hip_bf16.h>

#define SPIX 1000
#define NCLS 21
#define PP (512*512)          // pixels per image, 2^18
#define NB_IMG 8
#define EPB (NCLS*PP)         // elements per batch in pred

#define CHUNK 8192            // f-values per chunk (divides PP)
#define TPITCH 393            // odd pitch -> good LDS bank spread
#define TFLOATS (NCLS*TPITCH) // 8253

// ws layout (floats)
#define R_OFF   0                      // [8][21][1000]
#define TR_OFF  (NB_IMG*NCLS*SPIX)     // [8]
#define NS_OFF  (TR_OFF + NB_IMG)      // [1] norm^2
#define CNT_OFF (NS_OFF + 1)           // [1] valid count
#define WS_FLOATS (CNT_OFF + 1)

__global__ void normsq_kernel(const float* __restrict__ W, float* __restrict__ out, int n4) {
    const float4* W4 = (const float4*)W;
    float s = 0.f;
    for (int i = blockIdx.x * blockDim.x + threadIdx.x; i < n4; i += gridDim.x * blockDim.x) {
        float4 v = W4[i];
        s += v.x*v.x + v.y*v.y + v.z*v.z + v.w*v.w;
    }
    #pragma unroll
    for (int off = 32; off; off >>= 1) s += __shfl_xor(s, off);
    if ((threadIdx.x & 63) == 0) atomicAdd(out, s);
}

__global__ void count_kernel(const int* __restrict__ seg, float* __restrict__ out, int n4) {
    const int4* s4 = (const int4*)seg;
    int cnt = 0;
    for (int i = blockIdx.x * blockDim.x + threadIdx.x; i < n4; i += gridDim.x * blockDim.x) {
        int4 v = s4[i];
        cnt += ((unsigned)v.x < SPIX) + ((unsigned)v.y < SPIX) + ((unsigned)v.z < SPIX) + ((unsigned)v.w < SPIX);
    }
    float c = (float)cnt;
    #pragma unroll
    for (int off = 32; off; off >>= 1) c += __shfl_xor(c, off);
    if ((threadIdx.x & 63) == 0) atomicAdd(out, c);
}

// Output-order scatter: f = c*2^18 + p (f is the flat index of permuted pred).
// pred element = pred[b, f%21, f/21]; s = seg[b, p]. Block owns batch b and a
// fixed 8192-wide p-window; iterates c=0..20. Pred tile (21 runs of 392 floats)
// double-buffered in LDS; seg window cached in registers (loop-invariant).
__global__ __launch_bounds__(1024) void scatter_kernel(const float* __restrict__ pred,
                                                       const int* __restrict__ seg,
                                                       float* __restrict__ Rout) {
    __shared__ float Rl[NCLS * SPIX];       // 84 KB
    __shared__ float tile[2][TFLOATS];      // 2 x 33 KB
    const int b = blockIdx.x >> 5;
    const int sub = blockIdx.x & 31;
    const int tid = threadIdx.x;
    const float* pb = pred + (size_t)b * EPB;
    const int* segb = seg + (size_t)b * PP;
    const int p0 = sub * CHUNK;

    for (int i = tid; i < NCLS * SPIX; i += 1024) Rl[i] = 0.f;

    // cache seg window (same every c-iteration)
    int soff[8];
    #pragma unroll
    for (int k = 0; k < 8; ++k) {
        int s = segb[p0 + tid + k * 1024];
        soff[k] = ((unsigned)s < SPIX) ? s : -1;
    }

    // stage c=0 into tile[0]
    {
        const unsigned f0 = 0u * PP + p0;
        const int base = f0 / 21u;
        for (int i = tid; i < TFLOATS; i += 1024) {
            int cc = i / TPITCH;
            int j = i - cc * TPITCH;
            int sp = base + j; if (sp >= PP) sp = PP - 1;
            tile[0][i] = pb[cc * PP + sp];
        }
    }
    __syncthreads();

    float stg[9];
    for (int c = 0; c < NCLS; ++c) {
        const int cur = c & 1;
        // issue loads for next plane (latency hides under compute)
        if (c + 1 < NCLS) {
            const unsigned nf0 = (unsigned)(c + 1) * PP + p0;
            const int nbase = nf0 / 21u;
            #pragma unroll
            for (int k = 0; k < 9; ++k) {
                int i = tid + k * 1024;
                if (i < TFLOATS) {
                    int cc = i / TPITCH;
                    int j = i - cc * TPITCH;
                    int sp = nbase + j; if (sp >= PP) sp = PP - 1;
                    stg[k] = pb[cc * PP + sp];
                }
            }
        }
        // compute on tile[cur]
        const unsigned f0 = (unsigned)c * PP + p0;
        const int base = f0 / 21u;
        float* R_c = Rl + c * SPIX;
        #pragma unroll
        for (int k = 0; k < 8; ++k) {
            unsigned f = f0 + tid + k * 1024;
            unsigned sp = f / 21u;
            unsigned cc = f - sp * 21u;
            float v = tile[cur][cc * TPITCH + (sp - base)];
            if (soff[k] >= 0) atomicAdd(&R_c[soff[k]], v);
        }
        // write staged tile
        if (c + 1 < NCLS) {
            #pragma unroll
            for (int k = 0; k < 9; ++k) {
                int i = tid + k * 1024;
                if (i < TFLOATS) tile[cur ^ 1][i] = stg[k];
            }
        }
        __syncthreads();
    }

    float* Rb = Rout + (size_t)b * NCLS * SPIX;
    for (int i = tid; i < NCLS * SPIX; i += 1024) {
        float v = Rl[i];
        if (v != 0.f) atomicAdd(&Rb[i], v);
    }
}

// trace[b] = sum_{s,t} L[b,s,t] * sum_c R[b,c,s]*R[b,c,t]
// 512 threads, 8 waves, 4 L-rows per wave sharing each LDS R read.
__global__ __launch_bounds__(512) void trace_kernel(const float* __restrict__ L,
                                                    const float* __restrict__ R,
                                                    float* __restrict__ traces) {
    __shared__ float Rl[NCLS * SPIX];   // 84 KB
    const int b = blockIdx.y;
    const float* Rb = R + (size_t)b * NCLS * SPIX;
    for (int i = threadIdx.x; i < NCLS * SPIX; i += 512) Rl[i] = Rb[i];
    __syncthreads();

    const int wave = threadIdx.x >> 6;
    const int lane = threadIdx.x & 63;
    const float* Lb = L + (size_t)b * SPIX * SPIX;

    const int s0 = (blockIdx.x * 8 + wave) * 4;   // 32 blocks * 8 waves * 4 rows = 1024
    bool val[4];
    const float4* Lr[4];
    #pragma unroll
    for (int r = 0; r < 4; ++r) {
        int sr = s0 + r;
        val[r] = sr < SPIX;
        Lr[r] = (const float4*)(Lb + (size_t)(val[r] ? sr : (SPIX - 1)) * SPIX);
    }

    float acc[4][NCLS];
    #pragma unroll
    for (int r = 0; r < 4; ++r)
        #pragma unroll
        for (int c = 0; c < NCLS; ++c) acc[r][c] = 0.f;

    #pragma unroll
    for (int it = 0; it < 4; ++it) {
        int idx = it * 64 + lane;          // float4 index within row, 0..249
        if (idx < SPIX / 4) {
            float4 l[4];
            #pragma unroll
            for (int r = 0; r < 4; ++r)
                l[r] = val[r] ? Lr[r][idx] : make_float4(0.f, 0.f, 0.f, 0.f);
            #pragma unroll
            for (int c = 0; c < NCLS; ++c) {
                float4 rr = *(const float4*)&Rl[c * SPIX + idx * 4];
                #pragma unroll
                for (int r = 0; r < 4; ++r)
                    acc[r][c] += l[r].x * rr.x + l[r].y * rr.y + l[r].z * rr.z + l[r].w * rr.w;
            }
        }
    }

    float partial = 0.f;
    #pragma unroll
    for (int c = 0; c < NCLS; ++c)
        #pragma unroll
        for (int r = 0; r < 4; ++r)
            if (val[r]) partial += Rl[c * SPIX + s0 + r] * acc[r][c];

    #pragma unroll
    for (int off = 32; off; off >>= 1) partial += __shfl_xor(partial, off);
    if (lane == 0) atomicAdd(&traces[b], partial);
}

__global__ void finalize_kernel(const float* __restrict__ ws, float* __restrict__ out) {
    if (threadIdx.x == 0) {
        float denom = ws[CNT_OFF] + 1e-16f;
        float inv2 = 1.f / (denom * denom);
        float t = 0.f;
        for (int b = 0; b < NB_IMG; ++b) t += ws[TR_OFF + b];
        out[0] = (2.f / sqrtf(ws[NS_OFF])) * t * inv2 / (float)NB_IMG;
    }
}

extern "C" void kernel_launch(void* const* d_in, const int* in_sizes, int n_in,
                              void* d_out, int out_size, void* d_ws, size_t ws_size,
                              hipStream_t stream) {
    const float* pred = (const float*)d_in[0];
    const float* Wc   = (const float*)d_in[1];
    const float* Lc   = (const float*)d_in[2];
    const int*   seg  = (const int*)d_in[3];
    float* ws = (float*)d_ws;
    float* out = (float*)d_out;

    hipMemsetAsync(d_ws, 0, WS_FLOATS * sizeof(float), stream);

    normsq_kernel<<<1024, 256, 0, stream>>>(Wc, ws + NS_OFF, (NB_IMG * SPIX * SPIX) / 4);
    count_kernel<<<512, 256, 0, stream>>>(seg, ws + CNT_OFF, (NB_IMG * PP) / 4);

    scatter_kernel<<<256, 1024, 0, stream>>>(pred, seg, ws + R_OFF);

    trace_kernel<<<dim3(32, NB_IMG), 512, 0, stream>>>(Lc, ws + R_OFF, ws + TR_OFF);

    finalize_kernel<<<1, 64, 0, stream>>>(ws, out);
}

// Round 3
// 397.591 us; speedup vs baseline: 1.2791x; 1.0059x over previous
//
#include <hip/hip_runtime.h>
#include <hip/hip_bf16.h>

#define SPIX 1000
#define NCLS 21
#define PP (512*512)          // pixels per image, 2^18
#define NB_IMG 8
#define EPB (NCLS*PP)         // elements per batch in pred (= 21*2^18 f-values)

// scatter geometry: each block owns a contiguous 32768-wide f-window
#define FWIN 32768
#define BLKS_PER_B (EPB / FWIN)   // 168

// ws layout (floats)
#define R_OFF   0                      // [8][21][1000]
#define TR_OFF  (NB_IMG*NCLS*SPIX)     // [8]
#define NS_OFF  (TR_OFF + NB_IMG)      // [1] norm^2
#define CNT_OFF (NS_OFF + 1)           // [1] valid count
#define WS_FLOATS (CNT_OFF + 1)

__global__ void normsq_kernel(const float* __restrict__ W, float* __restrict__ out, int n4) {
    const float4* W4 = (const float4*)W;
    float s = 0.f;
    for (int i = blockIdx.x * blockDim.x + threadIdx.x; i < n4; i += gridDim.x * blockDim.x) {
        float4 v = W4[i];
        s += v.x*v.x + v.y*v.y + v.z*v.z + v.w*v.w;
    }
    #pragma unroll
    for (int off = 32; off; off >>= 1) s += __shfl_xor(s, off);
    if ((threadIdx.x & 63) == 0) atomicAdd(out, s);
}

__global__ void count_kernel(const int* __restrict__ seg, float* __restrict__ out, int n4) {
    const int4* s4 = (const int4*)seg;
    int cnt = 0;
    for (int i = blockIdx.x * blockDim.x + threadIdx.x; i < n4; i += gridDim.x * blockDim.x) {
        int4 v = s4[i];
        cnt += ((unsigned)v.x < SPIX) + ((unsigned)v.y < SPIX) + ((unsigned)v.z < SPIX) + ((unsigned)v.w < SPIX);
    }
    float c = (float)cnt;
    #pragma unroll
    for (int off = 32; off; off >>= 1) c += __shfl_xor(c, off);
    if ((threadIdx.x & 63) == 0) atomicAdd(out, c);
}

// f-window scatter: block owns f in [f0, f0+FWIN) of batch b.
//   p = f & (2^18-1)  -> consecutive across lanes -> coalesced int4 seg loads
//   c = f >> 18       -> constant (or c0/c0+1) within the window -> Rl[2][1000]
//   source element    -> pred[b, f%21, f/21]  (gather, L1-absorbed)
__global__ __launch_bounds__(512) void scatter_kernel(const float* __restrict__ pred,
                                                      const int* __restrict__ seg,
                                                      float* __restrict__ Rout) {
    __shared__ float Rl[2 * SPIX];   // 8 KB
    const int b = blockIdx.y;
    const int tid = threadIdx.x;
    const unsigned f0 = (unsigned)blockIdx.x * FWIN;
    const unsigned c0 = f0 >> 18;

    #pragma unroll
    for (int i = tid; i < 2 * SPIX; i += 512) Rl[i] = 0.f;
    __syncthreads();

    const float* pb = pred + (size_t)b * EPB;
    const int* segb = seg + (size_t)b * PP;

    #pragma unroll 4
    for (int it = 0; it < FWIN / (512 * 4); ++it) {        // 16 iterations
        unsigned f = f0 + (unsigned)(it * 512 + tid) * 4u;
        int4 sv = *(const int4*)(segb + (f & (PP - 1)));   // coalesced (f mult of 4, wrap-safe)
        #pragma unroll
        for (int k = 0; k < 4; ++k) {
            unsigned fk = f + k;
            unsigned sp = fk / 21u;                        // magic-mul
            unsigned ch = fk - sp * 21u;
            float v = pb[(ch << 18) + sp];
            int s = (&sv.x)[k];
            unsigned cc = (fk >> 18) - c0;                 // 0 or 1
            if ((unsigned)s < SPIX) atomicAdd(&Rl[cc * SPIX + s], v);
        }
    }
    __syncthreads();

    // rows c0, c0+1 are contiguous in Rout
    float* Rb = Rout + (size_t)b * NCLS * SPIX + (size_t)c0 * SPIX;
    for (int i = tid; i < 2 * SPIX; i += 512) {
        float v = Rl[i];
        if (v != 0.f) atomicAdd(&Rb[i], v);
    }
}

// trace[b] = sum_{s,t} L[b,s,t] * sum_c R[b,c,s]*R[b,c,t]
// 512 threads, 8 waves, 4 L-rows per wave sharing each LDS R read.
__global__ __launch_bounds__(512) void trace_kernel(const float* __restrict__ L,
                                                    const float* __restrict__ R,
                                                    float* __restrict__ traces) {
    __shared__ float Rl[NCLS * SPIX];   // 84 KB
    const int b = blockIdx.y;
    const float* Rb = R + (size_t)b * NCLS * SPIX;
    for (int i = threadIdx.x; i < NCLS * SPIX; i += 512) Rl[i] = Rb[i];
    __syncthreads();

    const int wave = threadIdx.x >> 6;
    const int lane = threadIdx.x & 63;
    const float* Lb = L + (size_t)b * SPIX * SPIX;

    const int s0 = (blockIdx.x * 8 + wave) * 4;   // 32 blocks * 8 waves * 4 rows = 1024
    bool val[4];
    const float4* Lr[4];
    #pragma unroll
    for (int r = 0; r < 4; ++r) {
        int sr = s0 + r;
        val[r] = sr < SPIX;
        Lr[r] = (const float4*)(Lb + (size_t)(val[r] ? sr : (SPIX - 1)) * SPIX);
    }

    float acc[4][NCLS];
    #pragma unroll
    for (int r = 0; r < 4; ++r)
        #pragma unroll
        for (int c = 0; c < NCLS; ++c) acc[r][c] = 0.f;

    #pragma unroll
    for (int it = 0; it < 4; ++it) {
        int idx = it * 64 + lane;          // float4 index within row, 0..249
        if (idx < SPIX / 4) {
            float4 l[4];
            #pragma unroll
            for (int r = 0; r < 4; ++r)
                l[r] = val[r] ? Lr[r][idx] : make_float4(0.f, 0.f, 0.f, 0.f);
            #pragma unroll
            for (int c = 0; c < NCLS; ++c) {
                float4 rr = *(const float4*)&Rl[c * SPIX + idx * 4];
                #pragma unroll
                for (int r = 0; r < 4; ++r)
                    acc[r][c] += l[r].x * rr.x + l[r].y * rr.y + l[r].z * rr.z + l[r].w * rr.w;
            }
        }
    }

    float partial = 0.f;
    #pragma unroll
    for (int c = 0; c < NCLS; ++c)
        #pragma unroll
        for (int r = 0; r < 4; ++r)
            if (val[r]) partial += Rl[c * SPIX + s0 + r] * acc[r][c];

    #pragma unroll
    for (int off = 32; off; off >>= 1) partial += __shfl_xor(partial, off);
    if (lane == 0) atomicAdd(&traces[b], partial);
}

__global__ void finalize_kernel(const float* __restrict__ ws, float* __restrict__ out) {
    if (threadIdx.x == 0) {
        float denom = ws[CNT_OFF] + 1e-16f;
        float inv2 = 1.f / (denom * denom);
        float t = 0.f;
        for (int b = 0; b < NB_IMG; ++b) t += ws[TR_OFF + b];
        out[0] = (2.f / sqrtf(ws[NS_OFF])) * t * inv2 / (float)NB_IMG;
    }
}

extern "C" void kernel_launch(void* const* d_in, const int* in_sizes, int n_in,
                              void* d_out, int out_size, void* d_ws, size_t ws_size,
                              hipStream_t stream) {
    const float* pred = (const float*)d_in[0];
    const float* Wc   = (const float*)d_in[1];
    const float* Lc   = (const float*)d_in[2];
    const int*   seg  = (const int*)d_in[3];
    float* ws = (float*)d_ws;
    float* out = (float*)d_out;

    hipMemsetAsync(d_ws, 0, WS_FLOATS * sizeof(float), stream);

    normsq_kernel<<<1024, 256, 0, stream>>>(Wc, ws + NS_OFF, (NB_IMG * SPIX * SPIX) / 4);
    count_kernel<<<512, 256, 0, stream>>>(seg, ws + CNT_OFF, (NB_IMG * PP) / 4);

    scatter_kernel<<<dim3(BLKS_PER_B, NB_IMG), 512, 0, stream>>>(pred, seg, ws + R_OFF);

    trace_kernel<<<dim3(32, NB_IMG), 512, 0, stream>>>(Lc, ws + R_OFF, ws + TR_OFF);

    finalize_kernel<<<1, 64, 0, stream>>>(ws, out);
}

// Round 4
// 396.898 us; speedup vs baseline: 1.2814x; 1.0017x over previous
//
#include <hip/hip_runtime.h>
#include <hip/hip_bf16.h>

#define SPIX 1000
#define NCLS 21
#define PP (512*512)          // pixels per image, 2^18
#define NB_IMG 8
#define EPB (NCLS*PP)         // elements per batch in pred (= 21*2^18 f-values)

// scatter geometry: each block owns a contiguous 32768-wide f-window
#define FWIN 32768
#define BLKS_PER_B (EPB / FWIN)   // 168

// ws layout (floats)
#define R_OFF   0                      // [8][21][1000]
#define TR_OFF  (NB_IMG*NCLS*SPIX)     // [8]
#define NS_OFF  (TR_OFF + NB_IMG)      // [1] norm^2
#define CNT_OFF (NS_OFF + 1)           // [1] valid count
#define WS_FLOATS (CNT_OFF + 1)

// native fp32 atomic add (ds_add_f32 / global_atomic_add_f32); plain atomicAdd
// compiles to a CAS loop without -munsafe-fp-atomics => ~50-100x slower.
__device__ __forceinline__ void fatomic_add(float* p, float v) {
    unsafeAtomicAdd(p, v);
}

__global__ void normsq_kernel(const float* __restrict__ W, float* __restrict__ out, int n4) {
    const float4* W4 = (const float4*)W;
    float s = 0.f;
    for (int i = blockIdx.x * blockDim.x + threadIdx.x; i < n4; i += gridDim.x * blockDim.x) {
        float4 v = W4[i];
        s += v.x*v.x + v.y*v.y + v.z*v.z + v.w*v.w;
    }
    #pragma unroll
    for (int off = 32; off; off >>= 1) s += __shfl_xor(s, off);
    if ((threadIdx.x & 63) == 0) fatomic_add(out, s);
}

__global__ void count_kernel(const int* __restrict__ seg, float* __restrict__ out, int n4) {
    const int4* s4 = (const int4*)seg;
    int cnt = 0;
    for (int i = blockIdx.x * blockDim.x + threadIdx.x; i < n4; i += gridDim.x * blockDim.x) {
        int4 v = s4[i];
        cnt += ((unsigned)v.x < SPIX) + ((unsigned)v.y < SPIX) + ((unsigned)v.z < SPIX) + ((unsigned)v.w < SPIX);
    }
    float c = (float)cnt;
    #pragma unroll
    for (int off = 32; off; off >>= 1) c += __shfl_xor(c, off);
    if ((threadIdx.x & 63) == 0) fatomic_add(out, c);
}

// f-window scatter: block owns f in [f0, f0+FWIN) of batch b.
//   p = f & (2^18-1)  -> consecutive across lanes -> coalesced int4 seg loads
//   c = f >> 18       -> constant (or c0/c0+1) within the window -> Rl[2][1000]
//   source element    -> pred[b, f%21, f/21]  (gather, L1-absorbed)
__global__ __launch_bounds__(512) void scatter_kernel(const float* __restrict__ pred,
                                                      const int* __restrict__ seg,
                                                      float* __restrict__ Rout) {
    __shared__ float Rl[2 * SPIX];   // 8 KB
    const int b = blockIdx.y;
    const int tid = threadIdx.x;
    const unsigned f0 = (unsigned)blockIdx.x * FWIN;
    const unsigned c0 = f0 >> 18;

    #pragma unroll
    for (int i = tid; i < 2 * SPIX; i += 512) Rl[i] = 0.f;
    __syncthreads();

    const float* pb = pred + (size_t)b * EPB;
    const int* segb = seg + (size_t)b * PP;

    #pragma unroll 4
    for (int it = 0; it < FWIN / (512 * 4); ++it) {        // 16 iterations
        unsigned f = f0 + (unsigned)(it * 512 + tid) * 4u;
        int4 sv = *(const int4*)(segb + (f & (PP - 1)));   // coalesced (f mult of 4, wrap-safe)
        #pragma unroll
        for (int k = 0; k < 4; ++k) {
            unsigned fk = f + k;
            unsigned sp = fk / 21u;                        // magic-mul
            unsigned ch = fk - sp * 21u;
            float v = pb[(ch << 18) + sp];
            int s = (&sv.x)[k];
            unsigned cc = (fk >> 18) - c0;                 // 0 or 1
            if ((unsigned)s < SPIX) fatomic_add(&Rl[cc * SPIX + s], v);
        }
    }
    __syncthreads();

    // rows c0, c0+1 are contiguous in Rout
    float* Rb = Rout + (size_t)b * NCLS * SPIX + (size_t)c0 * SPIX;
    for (int i = tid; i < 2 * SPIX; i += 512) {
        float v = Rl[i];
        if (v != 0.f) fatomic_add(&Rb[i], v);
    }
}

// trace[b] = sum_{s,t} L[b,s,t] * sum_c R[b,c,s]*R[b,c,t]
// 512 threads, 8 waves, 4 L-rows per wave sharing each LDS R read.
__global__ __launch_bounds__(512) void trace_kernel(const float* __restrict__ L,
                                                    const float* __restrict__ R,
                                                    float* __restrict__ traces) {
    __shared__ float Rl[NCLS * SPIX];   // 84 KB
    const int b = blockIdx.y;
    const float* Rb = R + (size_t)b * NCLS * SPIX;
    for (int i = threadIdx.x; i < NCLS * SPIX; i += 512) Rl[i] = Rb[i];
    __syncthreads();

    const int wave = threadIdx.x >> 6;
    const int lane = threadIdx.x & 63;
    const float* Lb = L + (size_t)b * SPIX * SPIX;

    const int s0 = (blockIdx.x * 8 + wave) * 4;   // 32 blocks * 8 waves * 4 rows = 1024
    bool val[4];
    const float4* Lr[4];
    #pragma unroll
    for (int r = 0; r < 4; ++r) {
        int sr = s0 + r;
        val[r] = sr < SPIX;
        Lr[r] = (const float4*)(Lb + (size_t)(val[r] ? sr : (SPIX - 1)) * SPIX);
    }

    float acc[4][NCLS];
    #pragma unroll
    for (int r = 0; r < 4; ++r)
        #pragma unroll
        for (int c = 0; c < NCLS; ++c) acc[r][c] = 0.f;

    #pragma unroll
    for (int it = 0; it < 4; ++it) {
        int idx = it * 64 + lane;          // float4 index within row, 0..249
        if (idx < SPIX / 4) {
            float4 l[4];
            #pragma unroll
            for (int r = 0; r < 4; ++r)
                l[r] = val[r] ? Lr[r][idx] : make_float4(0.f, 0.f, 0.f, 0.f);
            #pragma unroll
            for (int c = 0; c < NCLS; ++c) {
                float4 rr = *(const float4*)&Rl[c * SPIX + idx * 4];
                #pragma unroll
                for (int r = 0; r < 4; ++r)
                    acc[r][c] += l[r].x * rr.x + l[r].y * rr.y + l[r].z * rr.z + l[r].w * rr.w;
            }
        }
    }

    float partial = 0.f;
    #pragma unroll
    for (int c = 0; c < NCLS; ++c)
        #pragma unroll
        for (int r = 0; r < 4; ++r)
            if (val[r]) partial += Rl[c * SPIX + s0 + r] * acc[r][c];

    #pragma unroll
    for (int off = 32; off; off >>= 1) partial += __shfl_xor(partial, off);
    if (lane == 0) fatomic_add(&traces[b], partial);
}

__global__ void finalize_kernel(const float* __restrict__ ws, float* __restrict__ out) {
    if (threadIdx.x == 0) {
        float denom = ws[CNT_OFF] + 1e-16f;
        float inv2 = 1.f / (denom * denom);
        float t = 0.f;
        for (int b = 0; b < NB_IMG; ++b) t += ws[TR_OFF + b];
        out[0] = (2.f / sqrtf(ws[NS_OFF])) * t * inv2 / (float)NB_IMG;
    }
}

extern "C" void kernel_launch(void* const* d_in, const int* in_sizes, int n_in,
                              void* d_out, int out_size, void* d_ws, size_t ws_size,
                              hipStream_t stream) {
    const float* pred = (const float*)d_in[0];
    const float* Wc   = (const float*)d_in[1];
    const float* Lc   = (const float*)d_in[2];
    const int*   seg  = (const int*)d_in[3];
    float* ws = (float*)d_ws;
    float* out = (float*)d_out;

    hipMemsetAsync(d_ws, 0, WS_FLOATS * sizeof(float), stream);

    normsq_kernel<<<1024, 256, 0, stream>>>(Wc, ws + NS_OFF, (NB_IMG * SPIX * SPIX) / 4);
    count_kernel<<<512, 256, 0, stream>>>(seg, ws + CNT_OFF, (NB_IMG * PP) / 4);

    scatter_kernel<<<dim3(BLKS_PER_B, NB_IMG), 512, 0, stream>>>(pred, seg, ws + R_OFF);

    trace_kernel<<<dim3(32, NB_IMG), 512, 0, stream>>>(Lc, ws + R_OFF, ws + TR_OFF);

    finalize_kernel<<<1, 64, 0, stream>>>(ws, out);
}

// Round 5
// 251.397 us; speedup vs baseline: 2.0230x; 1.5788x over previous
//
#include <hip/hip_runtime.h>
#include <hip/hip_bf16.h>

#define SPIX 1000
#define NCLS 21
#define PP (512*512)          // pixels per image, 2^18
#define NB_IMG 8
#define EPB (NCLS*PP)         // elements per batch in pred (= 21*2^18 f-values)

// scatter geometry: contiguous 32768-wide f-window per block; 2^15 | 2^18 so
// the class row c = f>>18 is CONSTANT within a block.
#define FWIN 32768
#define BLKS_PER_B (EPB / FWIN)   // 168

// ws layout (floats)
#define R_OFF   0                      // [8][21][1000]
#define TR_OFF  (NB_IMG*NCLS*SPIX)     // [8]
#define NS_OFF  (TR_OFF + NB_IMG)      // [1] norm^2
#define CNT_OFF (NS_OFF + 1)           // [1] valid count
#define WS_FLOATS (CNT_OFF + 1)

__device__ __forceinline__ void fatomic_add(float* p, float v) {
    unsafeAtomicAdd(p, v);   // native ds_add_f32 / global_atomic_add_f32
}

// fused ||W||^2 + valid-count (independent grid halves)
__global__ void scalars_kernel(const float* __restrict__ W, const int* __restrict__ seg,
                               float* __restrict__ ns, float* __restrict__ cnt) {
    if (blockIdx.x < 1024) {
        const float4* W4 = (const float4*)W;
        const int n4 = (NB_IMG * SPIX * SPIX) / 4;
        float s = 0.f;
        for (int i = blockIdx.x * 256 + threadIdx.x; i < n4; i += 1024 * 256) {
            float4 v = W4[i];
            s += v.x*v.x + v.y*v.y + v.z*v.z + v.w*v.w;
        }
        #pragma unroll
        for (int off = 32; off; off >>= 1) s += __shfl_xor(s, off);
        if ((threadIdx.x & 63) == 0) fatomic_add(ns, s);
    } else {
        const int4* s4 = (const int4*)seg;
        const int n4 = (NB_IMG * PP) / 4;
        int c = 0;
        for (int i = (blockIdx.x - 1024) * 256 + threadIdx.x; i < n4; i += 512 * 256) {
            int4 v = s4[i];
            c += ((unsigned)v.x < SPIX) + ((unsigned)v.y < SPIX) + ((unsigned)v.z < SPIX) + ((unsigned)v.w < SPIX);
        }
        float f = (float)c;
        #pragma unroll
        for (int off = 32; off; off >>= 1) f += __shfl_xor(f, off);
        if ((threadIdx.x & 63) == 0) fatomic_add(cnt, f);
    }
}

// Scatter without the LDS-atomic pipe (measured: ~3.6 cyc per lane-atomic ->
// 260us wall). Wave-private R copies kill cross-wave races; an LDS claim
// marker resolves intra-wave duplicate bins; winners (~97%) use non-atomic
// banked read+add+write, losers fall back to ds_add. Wave lockstep sequences
// winner-RMW before loser-atomic on the same address -> exactly-once.
__global__ __launch_bounds__(512) void scatter_kernel(const float* __restrict__ pred,
                                                      const int* __restrict__ seg,
                                                      float* __restrict__ Rout) {
    __shared__ float    Rw[8][1024];   // wave-private accumulators, 32 KB
    __shared__ unsigned Mk[8][1024];   // wave-private claim markers, 32 KB
    const int b    = blockIdx.y;
    const int tid  = threadIdx.x;
    const int wave = tid >> 6;
    const unsigned lane = tid & 63;
    const unsigned f0 = (unsigned)blockIdx.x * FWIN;
    const unsigned c0 = f0 >> 18;            // constant class row for this block
    const unsigned p0 = f0 & (PP - 1);       // window start pixel (never wraps)

    for (int i = tid; i < 8 * 1024; i += 512) ((float*)Rw)[i] = 0.f;
    __syncthreads();

    volatile float*    vR = Rw[wave];
    volatile unsigned* vM = Mk[wave];
    float* aR = (float*)Rw[wave];

    const float* pb   = pred + (size_t)b * EPB;
    const int*   segb = seg + (size_t)b * PP + p0;

    for (int it = 0; it < FWIN / (512 * 4); ++it) {          // 16 iterations
        const int e0 = (it * 512 + tid) * 4;
        int4 sv = *(const int4*)(segb + e0);                 // coalesced
        const unsigned fk0 = f0 + (unsigned)e0;
        #pragma unroll
        for (int k = 0; k < 4; ++k) {
            unsigned fk = fk0 + k;
            unsigned sp = fk / 21u;                          // magic-mul
            unsigned ch = fk - sp * 21u;
            float v = pb[(ch << 18) + sp];                   // gather, L1-absorbed
            int s = (&sv.x)[k];
            if ((unsigned)s < SPIX) {
                vM[s] = lane;                                // claim (banked write)
                if (vM[s] == lane) {                         // won: non-atomic RMW
                    vR[s] = vR[s] + v;
                } else {                                     // rare collision
                    fatomic_add(&aR[s], v);
                }
            }
        }
    }
    __syncthreads();

    // merge 8 wave copies, one global atomic per bin
    float* Rb = Rout + (size_t)b * NCLS * SPIX + (size_t)c0 * SPIX;
    for (int i = tid; i < SPIX; i += 512) {
        float a = 0.f;
        #pragma unroll
        for (int w = 0; w < 8; ++w) a += Rw[w][i];
        fatomic_add(&Rb[i], a);
    }
}

// trace[b] = sum_{s,t} L[b,s,t] * sum_c R[b,c,s]*R[b,c,t]
__global__ __launch_bounds__(512) void trace_kernel(const float* __restrict__ L,
                                                    const float* __restrict__ R,
                                                    float* __restrict__ traces) {
    __shared__ float Rl[NCLS * SPIX];   // 84 KB
    const int b = blockIdx.y;
    const float* Rb = R + (size_t)b * NCLS * SPIX;
    for (int i = threadIdx.x; i < NCLS * SPIX; i += 512) Rl[i] = Rb[i];
    __syncthreads();

    const int wave = threadIdx.x >> 6;
    const int lane = threadIdx.x & 63;
    const float* Lb = L + (size_t)b * SPIX * SPIX;

    const int s0 = (blockIdx.x * 8 + wave) * 4;   // 32 blocks * 8 waves * 4 rows = 1024
    bool val[4];
    const float4* Lr[4];
    #pragma unroll
    for (int r = 0; r < 4; ++r) {
        int sr = s0 + r;
        val[r] = sr < SPIX;
        Lr[r] = (const float4*)(Lb + (size_t)(val[r] ? sr : (SPIX - 1)) * SPIX);
    }

    float acc[4][NCLS];
    #pragma unroll
    for (int r = 0; r < 4; ++r)
        #pragma unroll
        for (int c = 0; c < NCLS; ++c) acc[r][c] = 0.f;

    #pragma unroll
    for (int it = 0; it < 4; ++it) {
        int idx = it * 64 + lane;          // float4 index within row, 0..249
        if (idx < SPIX / 4) {
            float4 l[4];
            #pragma unroll
            for (int r = 0; r < 4; ++r)
                l[r] = val[r] ? Lr[r][idx] : make_float4(0.f, 0.f, 0.f, 0.f);
            #pragma unroll
            for (int c = 0; c < NCLS; ++c) {
                float4 rr = *(const float4*)&Rl[c * SPIX + idx * 4];
                #pragma unroll
                for (int r = 0; r < 4; ++r)
                    acc[r][c] += l[r].x * rr.x + l[r].y * rr.y + l[r].z * rr.z + l[r].w * rr.w;
            }
        }
    }

    float partial = 0.f;
    #pragma unroll
    for (int c = 0; c < NCLS; ++c)
        #pragma unroll
        for (int r = 0; r < 4; ++r)
            if (val[r]) partial += Rl[c * SPIX + s0 + r] * acc[r][c];

    #pragma unroll
    for (int off = 32; off; off >>= 1) partial += __shfl_xor(partial, off);
    if (lane == 0) fatomic_add(&traces[b], partial);
}

__global__ void finalize_kernel(const float* __restrict__ ws, float* __restrict__ out) {
    if (threadIdx.x == 0) {
        float denom = ws[CNT_OFF] + 1e-16f;
        float inv2 = 1.f / (denom * denom);
        float t = 0.f;
        for (int b = 0; b < NB_IMG; ++b) t += ws[TR_OFF + b];
        out[0] = (2.f / sqrtf(ws[NS_OFF])) * t * inv2 / (float)NB_IMG;
    }
}

extern "C" void kernel_launch(void* const* d_in, const int* in_sizes, int n_in,
                              void* d_out, int out_size, void* d_ws, size_t ws_size,
                              hipStream_t stream) {
    const float* pred = (const float*)d_in[0];
    const float* Wc   = (const float*)d_in[1];
    const float* Lc   = (const float*)d_in[2];
    const int*   seg  = (const int*)d_in[3];
    float* ws = (float*)d_ws;
    float* out = (float*)d_out;

    hipMemsetAsync(d_ws, 0, WS_FLOATS * sizeof(float), stream);

    scalars_kernel<<<1536, 256, 0, stream>>>(Wc, seg, ws + NS_OFF, ws + CNT_OFF);

    scatter_kernel<<<dim3(BLKS_PER_B, NB_IMG), 512, 0, stream>>>(pred, seg, ws + R_OFF);

    trace_kernel<<<dim3(32, NB_IMG), 512, 0, stream>>>(Lc, ws + R_OFF, ws + TR_OFF);

    finalize_kernel<<<1, 64, 0, stream>>>(ws, out);
}

// Round 6
// 159.316 us; speedup vs baseline: 3.1922x; 1.5780x over previous
//
#include <hip/hip_runtime.h>
#include <hip/hip_bf16.h>

#define SPIX 1000
#define NCLS 21
#define PP (512*512)          // pixels per image, 2^18
#define NB_IMG 8
#define EPB (NCLS*PP)         // elements per batch in pred (= 21*2^18 f-values)

// scatter geometry: contiguous 32768-wide f-window per block; 2^15 | 2^18 so
// the class row c = f>>18 is CONSTANT within a block.
#define FWIN 32768
#define BLKS_PER_B (EPB / FWIN)   // 168
#define DUMP 1000                 // garbage slot (rows sized 1024)

// ws layout (floats)
#define R_OFF   0                      // [8][21][1000]
#define TR_OFF  (NB_IMG*NCLS*SPIX)     // [8]
#define NS_OFF  (TR_OFF + NB_IMG)      // [1] norm^2
#define CNT_OFF (NS_OFF + 1)           // [1] valid count
#define CTR_OFF (CNT_OFF + 1)          // [1] trace-block completion counter
#define WS_FLOATS (CTR_OFF + 1)

__device__ __forceinline__ void fatomic_add(float* p, float v) {
    unsafeAtomicAdd(p, v);   // native ds_add_f32 / global_atomic_add_f32
}

// Scatter + (on blockIdx.y==8) the ||W||^2 and valid-count reductions.
// Scatter protocol (phase-batched claim, wave-private copies):
//   claims x4 -> claim-reads x4 -> RMW-reads x4 -> winner-writes x4 (branchless
//   dump-slot addressing) -> rare masked ds_add fallback. Wave in-order LDS
//   execution sequences winner RMW before loser atomic; lane-local dedup
//   guarantees at most one winning slot per (lane, bin).
__global__ __launch_bounds__(512, 4) void scatter_kernel(const float* __restrict__ pred,
                                                         const int* __restrict__ seg,
                                                         const float* __restrict__ W,
                                                         float* __restrict__ Rout,
                                                         float* __restrict__ ns,
                                                         float* __restrict__ cnt) {
    if (blockIdx.y == NB_IMG) {            // -------- scalars blocks --------
        if (blockIdx.x < 128) {
            const float4* W4 = (const float4*)W;
            const int n4 = (NB_IMG * SPIX * SPIX) / 4;
            float s = 0.f;
            for (int i = blockIdx.x * 512 + threadIdx.x; i < n4; i += 128 * 512) {
                float4 v = W4[i];
                s += v.x*v.x + v.y*v.y + v.z*v.z + v.w*v.w;
            }
            #pragma unroll
            for (int off = 32; off; off >>= 1) s += __shfl_xor(s, off);
            if ((threadIdx.x & 63) == 0) fatomic_add(ns, s);
        } else {
            const int4* s4 = (const int4*)seg;
            const int n4 = (NB_IMG * PP) / 4;
            int c = 0;
            for (int i = (blockIdx.x - 128) * 512 + threadIdx.x; i < n4; i += 40 * 512) {
                int4 v = s4[i];
                c += ((unsigned)v.x < SPIX) + ((unsigned)v.y < SPIX) + ((unsigned)v.z < SPIX) + ((unsigned)v.w < SPIX);
            }
            float f = (float)c;
            #pragma unroll
            for (int off = 32; off; off >>= 1) f += __shfl_xor(f, off);
            if ((threadIdx.x & 63) == 0) fatomic_add(cnt, f);
        }
        return;
    }
    // -------- scatter blocks --------
    __shared__ float          Rw[8][1024];   // wave-private accumulators, 32 KB
    __shared__ unsigned short Mk[8][1024];   // wave-private claim markers, 16 KB
    const int b    = blockIdx.y;
    const int tid  = threadIdx.x;
    const int wave = tid >> 6;
    const unsigned lane = tid & 63;
    const unsigned f0 = (unsigned)blockIdx.x * FWIN;
    const unsigned c0 = f0 >> 18;            // constant class row for this block
    const unsigned p0 = f0 & (PP - 1);       // window start pixel (never wraps)

    for (int i = tid; i < 8 * 1024; i += 512) ((float*)Rw)[i] = 0.f;
    __syncthreads();

    volatile float*          vR = Rw[wave];
    volatile unsigned short* vM = Mk[wave];
    float* aR = (float*)Rw[wave];

    const float* pb   = pred + (size_t)b * EPB;
    const int*   segb = seg + (size_t)b * PP + p0;

    for (int it = 0; it < FWIN / (512 * 4); ++it) {          // 16 iterations
        const int e0 = (it * 512 + tid) * 4;
        int4 sv = *(const int4*)(segb + e0);                 // coalesced
        const unsigned fk0 = f0 + (unsigned)e0;
        int sA[4]; float vA[4];
        #pragma unroll
        for (int k = 0; k < 4; ++k) {
            unsigned fk = fk0 + k;
            unsigned sp = fk / 21u;                          // magic-mul
            unsigned ch = fk - sp * 21u;
            vA[k] = pb[(ch << 18) + sp];                     // gather, L1-absorbed
            int s = (&sv.x)[k];
            sA[k] = ((unsigned)s < SPIX) ? s : DUMP;
        }
        // lane-local dedup: merge equal bins so a lane wins a bin at most once
        #pragma unroll
        for (int i = 0; i < 3; ++i)
            #pragma unroll
            for (int j = i + 1; j < 4; ++j) {
                bool e = (sA[j] == sA[i]) && (sA[i] != DUMP);
                vA[i] += e ? vA[j] : 0.f;
                sA[j]  = e ? DUMP  : sA[j];
            }
        // phase 1: claims (4 back-to-back ds_writes)
        #pragma unroll
        for (int k = 0; k < 4; ++k) vM[sA[k]] = (unsigned short)lane;
        // phase 2: claim readback (4 back-to-back ds_reads)
        unsigned short rd[4];
        #pragma unroll
        for (int k = 0; k < 4; ++k) rd[k] = vM[sA[k]];
        // phase 3: RMW reads (unconditional; losers read harmlessly)
        float od[4];
        #pragma unroll
        for (int k = 0; k < 4; ++k) od[k] = vR[sA[k]];
        // phase 4: winner writes, branchless (losers write garbage to DUMP)
        #pragma unroll
        for (int k = 0; k < 4; ++k) {
            bool win = (rd[k] == (unsigned short)lane);
            vR[win ? sA[k] : DUMP] = od[k] + vA[k];
        }
        asm volatile("" ::: "memory");   // order winner writes before fallbacks
        // phase 5: rare loser fallback (native ds_add, exec-masked)
        #pragma unroll
        for (int k = 0; k < 4; ++k) {
            if (rd[k] != (unsigned short)lane) fatomic_add(&aR[sA[k]], vA[k]);
        }
    }
    __syncthreads();

    // merge 8 wave copies, one global atomic per bin
    float* Rb = Rout + (size_t)b * NCLS * SPIX + (size_t)c0 * SPIX;
    for (int i = tid; i < SPIX; i += 512) {
        float a = 0.f;
        #pragma unroll
        for (int w = 0; w < 8; ++w) a += Rw[w][i];
        fatomic_add(&Rb[i], a);
    }
}

// trace[b] = sum_{s,t} L[b,s,t] * sum_c R[b,c,s]*R[b,c,t]; last block finalizes.
__global__ __launch_bounds__(512) void trace_kernel(const float* __restrict__ L,
                                                    const float* __restrict__ R,
                                                    float* __restrict__ traces,
                                                    const float* __restrict__ ns,
                                                    const float* __restrict__ cnt,
                                                    unsigned* __restrict__ ctr,
                                                    float* __restrict__ out) {
    __shared__ float Rl[NCLS * SPIX];   // 84 KB
    const int b = blockIdx.y;
    const float* Rb = R + (size_t)b * NCLS * SPIX;
    for (int i = threadIdx.x; i < NCLS * SPIX; i += 512) Rl[i] = Rb[i];
    __syncthreads();

    const int wave = threadIdx.x >> 6;
    const int lane = threadIdx.x & 63;
    const float* Lb = L + (size_t)b * SPIX * SPIX;

    const int s0 = (blockIdx.x * 8 + wave) * 4;   // 32 blocks * 8 waves * 4 rows = 1024
    bool val[4];
    const float4* Lr[4];
    #pragma unroll
    for (int r = 0; r < 4; ++r) {
        int sr = s0 + r;
        val[r] = sr < SPIX;
        Lr[r] = (const float4*)(Lb + (size_t)(val[r] ? sr : (SPIX - 1)) * SPIX);
    }

    float acc[4][NCLS];
    #pragma unroll
    for (int r = 0; r < 4; ++r)
        #pragma unroll
        for (int c = 0; c < NCLS; ++c) acc[r][c] = 0.f;

    #pragma unroll
    for (int it = 0; it < 4; ++it) {
        int idx = it * 64 + lane;          // float4 index within row, 0..249
        if (idx < SPIX / 4) {
            float4 l[4];
            #pragma unroll
            for (int r = 0; r < 4; ++r)
                l[r] = val[r] ? Lr[r][idx] : make_float4(0.f, 0.f, 0.f, 0.f);
            #pragma unroll
            for (int c = 0; c < NCLS; ++c) {
                float4 rr = *(const float4*)&Rl[c * SPIX + idx * 4];
                #pragma unroll
                for (int r = 0; r < 4; ++r)
                    acc[r][c] += l[r].x * rr.x + l[r].y * rr.y + l[r].z * rr.z + l[r].w * rr.w;
            }
        }
    }

    float partial = 0.f;
    #pragma unroll
    for (int c = 0; c < NCLS; ++c)
        #pragma unroll
        for (int r = 0; r < 4; ++r)
            if (val[r]) partial += Rl[c * SPIX + s0 + r] * acc[r][c];

    #pragma unroll
    for (int off = 32; off; off >>= 1) partial += __shfl_xor(partial, off);
    if (lane == 0) fatomic_add(&traces[b], partial);

    __syncthreads();                       // all waves' atomics drained (vmcnt before barrier)
    if (threadIdx.x == 0) {
        __threadfence();
        unsigned old = atomicAdd(ctr, 1u);
        if (old == 32u * NB_IMG - 1u) {    // last block finalizes
            __threadfence();
            float t = 0.f;
            #pragma unroll
            for (int i = 0; i < NB_IMG; ++i)
                t += __hip_atomic_load(&traces[i], __ATOMIC_RELAXED, __HIP_MEMORY_SCOPE_AGENT);
            float denom = cnt[0] + 1e-16f;
            out[0] = (2.f / sqrtf(ns[0])) * t / (denom * denom) / (float)NB_IMG;
        }
    }
}

extern "C" void kernel_launch(void* const* d_in, const int* in_sizes, int n_in,
                              void* d_out, int out_size, void* d_ws, size_t ws_size,
                              hipStream_t stream) {
    const float* pred = (const float*)d_in[0];
    const float* Wc   = (const float*)d_in[1];
    const float* Lc   = (const float*)d_in[2];
    const int*   seg  = (const int*)d_in[3];
    float* ws = (float*)d_ws;
    float* out = (float*)d_out;

    hipMemsetAsync(d_ws, 0, WS_FLOATS * sizeof(float), stream);

    scatter_kernel<<<dim3(BLKS_PER_B, NB_IMG + 1), 512, 0, stream>>>(
        pred, seg, Wc, ws + R_OFF, ws + NS_OFF, ws + CNT_OFF);

    trace_kernel<<<dim3(32, NB_IMG), 512, 0, stream>>>(
        Lc, ws + R_OFF, ws + TR_OFF, ws + NS_OFF, ws + CNT_OFF,
        (unsigned*)(ws + CTR_OFF), out);
}